// Round 20
// baseline (2405.131 us; speedup 1.0000x reference)
//
#include <hip/hip_runtime.h>
#include <math.h>

// LSTM B=128,T=1024,D=64,H=256,C=6 — R20: flattened LDS schedule.
//
// R19: lstm step = 5040cy but pipes only need ~2100 (VALU 1800, LDS ~2100)
// -> ~2900cy exposed latency: h-rotation lead 4 groups ~= LDS latency, and
// all 8 tail GT groups bunched at step end (LDS burst + short tw lead).
// R20 (lstm only; xg_gemm/out_proj byte-identical to R19):
//  * k-range OWNERSHIP reassigned: 32 uniform slots, h group g at slot g;
//    slots 0-7 = V pairs 0..31; slots 8-31 = [A,A,GT]x8 with tail k-groups
//    {10,13,16,19,22,25,28,31} (kb = 80+24*jq) -> LDS reads evenly spread
//  * h slots 6-deep (~300cy lead); tw dbuf primed in the LDS-idle V phase,
//    reloads 6 slots ahead (tail weights are time-invariant)
//  * regs: 128 wV + 24 hs + 32 qbank + 32 tw + ~30 misc ~= 246 < 256
// Numerics identical: absmax 3.9e-3.

#define Tt 1024
#define Dd 64
#define Hh 256
#define G4 1024
#define Cc 6
#define BT (128 * 1024)
#define XG_BYTES ((size_t)BT * G4 * 2)   // 256 MB f16

typedef _Float16 f16x2 __attribute__((ext_vector_type(2)));

__device__ __forceinline__ float dot2(f16x2 a, f16x2 b, float c) {
#if __has_builtin(__builtin_amdgcn_fdot2)
    return __builtin_amdgcn_fdot2(a, b, c, false);
#else
    return c + (float)a.x * (float)b.x + (float)a.y * (float)b.y;
#endif
}
__device__ __forceinline__ float sigm(float p) { return 1.0f / (1.0f + __expf(-p)); }
__device__ __forceinline__ float tanh_fast(float p) {
    return 1.0f - 2.0f / (__expf(2.0f * p) + 1.0f);
}
__device__ __forceinline__ unsigned short f2h(float v) {
    _Float16 h = (_Float16)v;
    return __builtin_bit_cast(unsigned short, h);
}
__device__ __forceinline__ float h2f(unsigned short u) {
    return (float)__builtin_bit_cast(_Float16, u);
}
__device__ __forceinline__ f16x2 bcf(float v) { return __builtin_bit_cast(f16x2, v); }
__device__ __forceinline__ f16x2 bcu(unsigned int v) { return __builtin_bit_cast(f16x2, v); }
__device__ __forceinline__ unsigned int packh(float a, float b) {
    return (unsigned int)f2h(a) | ((unsigned int)f2h(b) << 16);
}

// ---------------- stage 1: xg = x @ Wx + bias (f16 dot2, R19) --------------
__global__ __launch_bounds__(256) void xg_gemm(
    const float* __restrict__ x, const float* __restrict__ Wx,
    const float* __restrict__ bias, unsigned short* __restrict__ xg)
{
    __shared__ unsigned int xs[64][33];
    __shared__ unsigned int wsl[32][256];

    const int tid = threadIdx.x;
    const long r0 = (long)blockIdx.x * 64;
    const int  c0 = blockIdx.y * 256;

    #pragma unroll
    for (int it = 0; it < 4; ++it) {
        int i = tid + it * 256;
        int row = i >> 4, f4 = i & 15;
        float4 v = *(const float4*)(x + (r0 + row) * Dd + f4 * 4);
        xs[row][2 * f4]     = packh(v.x, v.y);
        xs[row][2 * f4 + 1] = packh(v.z, v.w);
    }
    #pragma unroll
    for (int it = 0; it < 8; ++it) {
        int i = tid + it * 256;
        int kp = i >> 6, cq = i & 63;
        float4 a = *(const float4*)(Wx + (long)(2 * kp) * G4 + c0 + cq * 4);
        float4 b = *(const float4*)(Wx + (long)(2 * kp + 1) * G4 + c0 + cq * 4);
        wsl[kp][cq * 4 + 0] = packh(a.x, b.x);
        wsl[kp][cq * 4 + 1] = packh(a.y, b.y);
        wsl[kp][cq * 4 + 2] = packh(a.z, b.z);
        wsl[kp][cq * 4 + 3] = packh(a.w, b.w);
    }
    __syncthreads();

    const int tr = tid & 31, cg = tid >> 5;
    float acc0[32], acc1[32];
    #pragma unroll
    for (int c = 0; c < 32; ++c) {
        float bv = bias[c0 + cg * 32 + c];
        acc0[c] = bv; acc1[c] = bv;
    }
    for (int kp = 0; kp < 32; ++kp) {
        f16x2 u0 = bcu(xs[tr][kp]);
        f16x2 u1 = bcu(xs[tr + 32][kp]);
        const uint4* wr = (const uint4*)&wsl[kp][cg * 32];
        #pragma unroll
        for (int q = 0; q < 8; ++q) {
            uint4 w = wr[q];
            acc0[4*q+0] = dot2(u0, bcu(w.x), acc0[4*q+0]);
            acc0[4*q+1] = dot2(u0, bcu(w.y), acc0[4*q+1]);
            acc0[4*q+2] = dot2(u0, bcu(w.z), acc0[4*q+2]);
            acc0[4*q+3] = dot2(u0, bcu(w.w), acc0[4*q+3]);
            acc1[4*q+0] = dot2(u1, bcu(w.x), acc1[4*q+0]);
            acc1[4*q+1] = dot2(u1, bcu(w.y), acc1[4*q+1]);
            acc1[4*q+2] = dot2(u1, bcu(w.z), acc1[4*q+2]);
            acc1[4*q+3] = dot2(u1, bcu(w.w), acc1[4*q+3]);
        }
    }
    {
        unsigned int ow[16];
        #pragma unroll
        for (int c2 = 0; c2 < 16; ++c2) ow[c2] = packh(acc0[2*c2], acc0[2*c2+1]);
        uint4* dst = (uint4*)(xg + (r0 + tr) * G4 + c0 + cg * 32);
        dst[0] = make_uint4(ow[0], ow[1], ow[2], ow[3]);
        dst[1] = make_uint4(ow[4], ow[5], ow[6], ow[7]);
        dst[2] = make_uint4(ow[8], ow[9], ow[10], ow[11]);
        dst[3] = make_uint4(ow[12], ow[13], ow[14], ow[15]);
    }
    {
        unsigned int ow[16];
        #pragma unroll
        for (int c2 = 0; c2 < 16; ++c2) ow[c2] = packh(acc1[2*c2], acc1[2*c2+1]);
        uint4* dst = (uint4*)(xg + (r0 + tr + 32) * G4 + c0 + cg * 32);
        dst[0] = make_uint4(ow[0], ow[1], ow[2], ow[3]);
        dst[1] = make_uint4(ow[4], ow[5], ow[6], ow[7]);
        dst[2] = make_uint4(ow[8], ow[9], ow[10], ow[11]);
        dst[3] = make_uint4(ow[12], ow[13], ow[14], ow[15]);
    }
}

// ---------------- stage 3: output projection (post-pass) -------------------
__global__ __launch_bounds__(256) void out_proj(
    const unsigned short* __restrict__ hs,
    const float* __restrict__ Wout,
    const float* __restrict__ bout,
    float* __restrict__ out)
{
    __shared__ float wt[Cc][Hh];
    const int tid = threadIdx.x;
    for (int i = tid; i < Cc * Hh; i += 256) wt[i % Cc][i / Cc] = Wout[i];
    __syncthreads();

    const int b = blockIdx.x;
    const int t = blockIdx.y * 256 + tid;
    const uint4* h4 = (const uint4*)(hs + ((long)b * Tt + t) * G4);
    float a0 = bout[0], a1 = bout[1], a2 = bout[2];
    float a3 = bout[3], a4 = bout[4], a5 = bout[5];
    #pragma unroll
    for (int j = 0; j < 32; ++j) {
        uint4 hv = h4[j];
        const unsigned int hw[4] = { hv.x, hv.y, hv.z, hv.w };
        #pragma unroll
        for (int q = 0; q < 4; ++q) {
            float hlo = h2f((unsigned short)(hw[q] & 0xffff));
            float hhi = h2f((unsigned short)(hw[q] >> 16));
            int m = j * 8 + 2 * q;
            a0 += hlo * wt[0][m] + hhi * wt[0][m + 1];
            a1 += hlo * wt[1][m] + hhi * wt[1][m + 1];
            a2 += hlo * wt[2][m] + hhi * wt[2][m + 1];
            a3 += hlo * wt[3][m] + hhi * wt[3][m + 1];
            a4 += hlo * wt[4][m] + hhi * wt[4][m + 1];
            a5 += hlo * wt[5][m] + hhi * wt[5][m + 1];
        }
    }
    float* orow = out + ((long)b * Tt + t) * Cc;
    orow[0] = a0; orow[1] = a1; orow[2] = a2;
    orow[3] = a3; orow[4] = a4; orow[5] = a5;
}

// ---------------- stage 2: recurrence (R20 flattened schedule) --------------
// k-group g = k rows 8g..8g+7 = pairs 4g..4g+3; h group g = hvf4[g].
// V: groups 0..7 (pairs 0..31). GT (LDS): groups 10,13,16,19,22,25,28,31
// (jq=0..7, kb=80+24jq). A (AGPR): the remaining 16 groups.

#define WLOADV4(i) \
  const f16x2 wA_##i = f16x2{(_Float16)Wh[(2*(i))*G4 + colA], (_Float16)Wh[(2*(i)+1)*G4 + colA]}; \
  const f16x2 wB_##i = f16x2{(_Float16)Wh[(2*(i))*G4 + colB], (_Float16)Wh[(2*(i)+1)*G4 + colB]}; \
  const f16x2 wC_##i = f16x2{(_Float16)Wh[(2*(i))*G4 + colC], (_Float16)Wh[(2*(i)+1)*G4 + colC]}; \
  const f16x2 wD_##i = f16x2{(_Float16)Wh[(2*(i))*G4 + colD], (_Float16)Wh[(2*(i)+1)*G4 + colD]};

#define AW1(dst, cix, i) { \
    f16x2 t_ = f16x2{(_Float16)Wh[(2*(i))*G4 + (cix)], (_Float16)Wh[(2*(i)+1)*G4 + (cix)]}; \
    asm volatile("v_accvgpr_write_b32 %0, %1" : "=a"(dst) : "v"(__builtin_bit_cast(float, t_))); }

#define WLOADA4(i) \
  float awA_##i, awB_##i, awC_##i, awD_##i; \
  AW1(awA_##i, colA, i) AW1(awB_##i, colB, i) \
  AW1(awC_##i, colC, i) AW1(awD_##i, colD, i)

#define REPV32(M) \
  M(0) M(1) M(2) M(3) M(4) M(5) M(6) M(7) \
  M(8) M(9) M(10) M(11) M(12) M(13) M(14) M(15) \
  M(16) M(17) M(18) M(19) M(20) M(21) M(22) M(23) \
  M(24) M(25) M(26) M(27) M(28) M(29) M(30) M(31)

// A groups: 8,9,11,12,14,15,17,18,20,21,23,24,26,27,29,30 -> pairs 4g..4g+3
#define REPA64(M) \
  M(32) M(33) M(34) M(35) M(36) M(37) M(38) M(39) \
  M(44) M(45) M(46) M(47) M(48) M(49) M(50) M(51) \
  M(56) M(57) M(58) M(59) M(60) M(61) M(62) M(63) \
  M(68) M(69) M(70) M(71) M(72) M(73) M(74) M(75) \
  M(80) M(81) M(82) M(83) M(84) M(85) M(86) M(87) \
  M(92) M(93) M(94) M(95) M(96) M(97) M(98) M(99) \
  M(104) M(105) M(106) M(107) M(108) M(109) M(110) M(111) \
  M(116) M(117) M(118) M(119) M(120) M(121) M(122) M(123)

#define DOTPV(i, hh) { f16x2 h_ = (hh); \
    aA = dot2(h_, wA_##i, aA); aB = dot2(h_, wB_##i, aB); \
    aC = dot2(h_, wC_##i, aC); aD = dot2(h_, wD_##i, aD); }

#define GV(s, n, i0,i1,i2,i3) { \
    DOTPV(i0, bcf(s.x)) DOTPV(i1, bcf(s.y)) \
    DOTPV(i2, bcf(s.z)) DOTPV(i3, bcf(s.w)) \
    s = hvf4[n]; }

#define ARD(dst, src) \
    asm volatile("v_accvgpr_read_b32 %0, %1" : "=v"(dst) : "a"(src));

#define AREADG(bk, i0,i1,i2,i3) \
    ARD(qA##bk##_0, awA_##i0) ARD(qB##bk##_0, awB_##i0) ARD(qC##bk##_0, awC_##i0) ARD(qD##bk##_0, awD_##i0) \
    ARD(qA##bk##_1, awA_##i1) ARD(qB##bk##_1, awB_##i1) ARD(qC##bk##_1, awC_##i1) ARD(qD##bk##_1, awD_##i1) \
    ARD(qA##bk##_2, awA_##i2) ARD(qB##bk##_2, awB_##i2) ARD(qC##bk##_2, awC_##i2) ARD(qD##bk##_2, awD_##i2) \
    ARD(qA##bk##_3, awA_##i3) ARD(qB##bk##_3, awB_##i3) ARD(qC##bk##_3, awC_##i3) ARD(qD##bk##_3, awD_##i3)

#define ADOTSG(bk, hs) { \
    f16x2 h0 = bcf(hs.x), h1 = bcf(hs.y), h2 = bcf(hs.z), h3 = bcf(hs.w); \
    aA = dot2(h0, bcf(qA##bk##_0), aA); aB = dot2(h0, bcf(qB##bk##_0), aB); \
    aC = dot2(h0, bcf(qC##bk##_0), aC); aD = dot2(h0, bcf(qD##bk##_0), aD); \
    aA = dot2(h1, bcf(qA##bk##_1), aA); aB = dot2(h1, bcf(qB##bk##_1), aB); \
    aC = dot2(h1, bcf(qC##bk##_1), aC); aD = dot2(h1, bcf(qD##bk##_1), aD); \
    aA = dot2(h2, bcf(qA##bk##_2), aA); aB = dot2(h2, bcf(qB##bk##_2), aB); \
    aC = dot2(h2, bcf(qC##bk##_2), aC); aD = dot2(h2, bcf(qD##bk##_2), aD); \
    aA = dot2(h3, bcf(qA##bk##_3), aA); aB = dot2(h3, bcf(qB##bk##_3), aB); \
    aC = dot2(h3, bcf(qC##bk##_3), aC); aD = dot2(h3, bcf(qD##bk##_3), aD); }

#define TWL(s, jq) { twA##s = wl4[jq][colA]; twB##s = wl4[jq][colB]; \
                     twC##s = wl4[jq][colC]; twD##s = wl4[jq][colD]; }

#define GT(hs, s) { \
    f16x2 h0 = bcf(hs.x), h1 = bcf(hs.y), h2 = bcf(hs.z), h3 = bcf(hs.w); \
    aA = dot2(h0, bcu(twA##s.x), aA); aA = dot2(h1, bcu(twA##s.y), aA); \
    aA = dot2(h2, bcu(twA##s.z), aA); aA = dot2(h3, bcu(twA##s.w), aA); \
    aB = dot2(h0, bcu(twB##s.x), aB); aB = dot2(h1, bcu(twB##s.y), aB); \
    aB = dot2(h2, bcu(twB##s.z), aB); aB = dot2(h3, bcu(twB##s.w), aB); \
    aC = dot2(h0, bcu(twC##s.x), aC); aC = dot2(h1, bcu(twC##s.y), aC); \
    aC = dot2(h2, bcu(twC##s.z), aC); aC = dot2(h3, bcu(twC##s.w), aC); \
    aD = dot2(h0, bcu(twD##s.x), aD); aD = dot2(h1, bcu(twD##s.y), aD); \
    aD = dot2(h2, bcu(twD##s.z), aD); aD = dot2(h3, bcu(twD##s.w), aD); }

__global__ __launch_bounds__(256, 1) void lstm_xg(
    unsigned short* __restrict__ xg,        // [B,T,1024] f16 in + h out
    const float* __restrict__ Wh)           // [H,4H]
{
    __shared__ alignas(16) unsigned short h_buf[2][Hh];
    __shared__ uint4 wl4[8][G4];       // tail groups {10,13,..,31}, 128 KB

    const int tid  = threadIdx.x;
    const int b    = blockIdx.x;
    const int colA = tid;
    const int colB = tid + 256;
    const int colC = tid + 512;
    const int colD = tid + 768;

    // ---- prologue ----
    REPV32(WLOADV4)
    REPA64(WLOADA4)

    #pragma unroll
    for (int jq = 0; jq < 8; ++jq) {   // tail group g=10+3jq: k rows 8g..8g+7
        const int kb = 80 + 24 * jq;
        wl4[jq][colA] = make_uint4(
            packh(Wh[(kb+0)*G4 + colA], Wh[(kb+1)*G4 + colA]),
            packh(Wh[(kb+2)*G4 + colA], Wh[(kb+3)*G4 + colA]),
            packh(Wh[(kb+4)*G4 + colA], Wh[(kb+5)*G4 + colA]),
            packh(Wh[(kb+6)*G4 + colA], Wh[(kb+7)*G4 + colA]));
        wl4[jq][colB] = make_uint4(
            packh(Wh[(kb+0)*G4 + colB], Wh[(kb+1)*G4 + colB]),
            packh(Wh[(kb+2)*G4 + colB], Wh[(kb+3)*G4 + colB]),
            packh(Wh[(kb+4)*G4 + colB], Wh[(kb+5)*G4 + colB]),
            packh(Wh[(kb+6)*G4 + colB], Wh[(kb+7)*G4 + colB]));
        wl4[jq][colC] = make_uint4(
            packh(Wh[(kb+0)*G4 + colC], Wh[(kb+1)*G4 + colC]),
            packh(Wh[(kb+2)*G4 + colC], Wh[(kb+3)*G4 + colC]),
            packh(Wh[(kb+4)*G4 + colC], Wh[(kb+5)*G4 + colC]),
            packh(Wh[(kb+6)*G4 + colC], Wh[(kb+7)*G4 + colC]));
        wl4[jq][colD] = make_uint4(
            packh(Wh[(kb+0)*G4 + colD], Wh[(kb+1)*G4 + colD]),
            packh(Wh[(kb+2)*G4 + colD], Wh[(kb+3)*G4 + colD]),
            packh(Wh[(kb+4)*G4 + colD], Wh[(kb+5)*G4 + colD]),
            packh(Wh[(kb+6)*G4 + colD], Wh[(kb+7)*G4 + colD]));
    }
    h_buf[0][tid] = 0;

    unsigned short* xgB = xg + (long)b * Tt * G4;
    unsigned short xgA = xgB[colA], xgBv = xgB[colB];
    unsigned short xgC = xgB[colC], xgD = xgB[colD];
    float c_state = 0.0f;
    int par = 0;
    __syncthreads();

    // ---- time loop: 32 uniform slots, h group g at slot g ----
    for (int t = 0; t < Tt; ++t) {
        unsigned short nA = 0, nB = 0, nC = 0, nD = 0;
        if (t + 1 < Tt) {
            const unsigned short* xn = xgB + (long)(t + 1) * G4;
            nA = xn[colA]; nB = xn[colB]; nC = xn[colC]; nD = xn[colD];
        }

        const float4* hvf4 = (const float4*)h_buf[par];
        float aA = 0.f, aB = 0.f, aC = 0.f, aD = 0.f;

        float qA0_0, qB0_0, qC0_0, qD0_0, qA0_1, qB0_1, qC0_1, qD0_1;
        float qA0_2, qB0_2, qC0_2, qD0_2, qA0_3, qB0_3, qC0_3, qD0_3;
        float qA1_0, qB1_0, qC1_0, qD1_0, qA1_1, qB1_1, qC1_1, qD1_1;
        float qA1_2, qB1_2, qC1_2, qD1_2, qA1_3, qB1_3, qC1_3, qD1_3;
        uint4 twA0, twB0, twC0, twD0, twA1, twB1, twC1, twD1;

        // prime: 6 h slots, 2 tail-weight buffers (LDS-idle window)
        float4 hs0 = hvf4[0], hs1 = hvf4[1], hs2 = hvf4[2];
        float4 hs3 = hvf4[3], hs4 = hvf4[4], hs5 = hvf4[5];
        TWL(0, 0)  TWL(1, 1)

        // V phase: slots 0..7 (groups 0..7), rotate to slot+6
        GV(hs0, 6,   0, 1, 2, 3)   GV(hs1, 7,   4, 5, 6, 7)
        GV(hs2, 8,   8, 9,10,11)   GV(hs3, 9,  12,13,14,15)
        GV(hs4, 10, 16,17,18,19)   GV(hs5, 11, 20,21,22,23)
        GV(hs0, 12, 24,25,26,27)   GV(hs1, 13, 28,29,30,31)

        // prime A-bank 0 with group 8 (pairs 32..35)
        AREADG(0, 32,33,34,35)
        // slots 8..31: [A, A, GT] x 8
        AREADG(1, 36,37,38,39)     ADOTSG(0, hs2)  hs2 = hvf4[14];   // s8:  g8
        AREADG(0, 44,45,46,47)     ADOTSG(1, hs3)  hs3 = hvf4[15];   // s9:  g9
        GT(hs4, 0)  hs4 = hvf4[16];  TWL(0, 2)                       // s10: g10
        AREADG(1, 48,49,50,51)     ADOTSG(0, hs5)  hs5 = hvf4[17];   // s11: g11
        AREADG(0, 56,57,58,59)     ADOTSG(1, hs0)  hs0 = hvf4[18];   // s12: g12
        GT(hs1, 1)  hs1 = hvf4[19];  TWL(1, 3)                       // s13: g13
        AREADG(1, 60,61,62,63)     ADOTSG(0, hs2)  hs2 = hvf4[20];   // s14: g14
        AREADG(0, 68,69,70,71)     ADOTSG(1, hs3)  hs3 = hvf4[21];   // s15: g15
        GT(hs4, 0)  hs4 = hvf4[22];  TWL(0, 4)                       // s16: g16
        AREADG(1, 72,73,74,75)     ADOTSG(0, hs5)  hs5 = hvf4[23];   // s17: g17
        AREADG(0, 80,81,82,83)     ADOTSG(1, hs0)  hs0 = hvf4[24];   // s18: g18
        GT(hs1, 1)  hs1 = hvf4[25];  TWL(1, 5)                       // s19: g19
        AREADG(1, 84,85,86,87)     ADOTSG(0, hs2)  hs2 = hvf4[26];   // s20: g20
        AREADG(0, 92,93,94,95)     ADOTSG(1, hs3)  hs3 = hvf4[27];   // s21: g21
        GT(hs4, 0)  hs4 = hvf4[28];  TWL(0, 6)                       // s22: g22
        AREADG(1, 96,97,98,99)     ADOTSG(0, hs5)  hs5 = hvf4[29];   // s23: g23
        AREADG(0, 104,105,106,107) ADOTSG(1, hs0)  hs0 = hvf4[30];   // s24: g24
        GT(hs1, 1)  hs1 = hvf4[31];  TWL(1, 7)                       // s25: g25
        AREADG(1, 108,109,110,111) ADOTSG(0, hs2)                    // s26: g26
        AREADG(0, 116,117,118,119) ADOTSG(1, hs3)                    // s27: g27
        GT(hs4, 0)                                                   // s28: g28
        AREADG(1, 120,121,122,123) ADOTSG(0, hs5)                    // s29: g29
                                   ADOTSG(1, hs0)                    // s30: g30
        GT(hs1, 1)                                                   // s31: g31

        float ig = sigm(h2f(xgA) + aA);
        float fg = sigm(h2f(xgBv) + aB);
        float gg = tanh_fast(h2f(xgC) + aC);
        float og = sigm(h2f(xgD) + aD);
        c_state = fg * c_state + ig * gg;
        float hval = og * tanh_fast(c_state);

        unsigned short hb = f2h(hval);
        h_buf[par ^ 1][tid] = hb;
        xgB[(long)t * G4 + tid] = hb;
        __syncthreads();

        xgA = nA; xgBv = nB; xgC = nC; xgD = nD;
        par ^= 1;
    }
}

// ---------------- fallback: R2 single-block kernel (no ws needed) ----------
__global__ __launch_bounds__(1024) void lstm_fused(
    const float* __restrict__ x, const float* __restrict__ Wx,
    const float* __restrict__ Wh, const float* __restrict__ bias,
    const float* __restrict__ Wout, const float* __restrict__ bout,
    float* __restrict__ out)
{
    __shared__ float h_lds[Hh];
    __shared__ float gates_lds[G4];
    __shared__ float x_lds[2][Dd];
    __shared__ float wout_t[Cc][Hh];
    __shared__ float bout_l[Cc];
    const int tid = threadIdx.x;
    const int b   = blockIdx.x;
    float wx[Dd];
    #pragma unroll
    for (int d = 0; d < Dd; ++d) wx[d] = Wx[d * G4 + tid];
    const float bj = bias[tid];
    if (tid < Hh) h_lds[tid] = 0.0f;
    for (int i = tid; i < Cc * Hh; i += 1024) wout_t[i % Cc][i / Cc] = Wout[i];
    if (tid < Cc) bout_l[tid] = bout[tid];
    const float* xB = x + (long)b * Tt * Dd;
    if (tid < Dd) x_lds[0][tid] = xB[tid];
    float c_state = 0.0f;
    __syncthreads();
    const float* WhB = Wh + tid;
    for (int t = 0; t < Tt; ++t) {
        float gg = bj;
        const float* xr = x_lds[t & 1];
        #pragma unroll
        for (int d = 0; d < Dd; ++d) gg += xr[d] * wx[d];
        #pragma unroll 8
        for (int k = 0; k < Hh; ++k) gg += h_lds[k] * WhB[k * G4];
        float a;
        if (tid < 2 * Hh)      a = 1.0f / (1.0f + expf(-gg));
        else if (tid < 3 * Hh) a = tanhf(gg);
        else                   a = 1.0f / (1.0f + expf(-gg));
        gates_lds[tid] = a;
        __syncthreads();
        if (tid < Hh) {
            float iv = gates_lds[tid], fv = gates_lds[tid + Hh];
            float gv = gates_lds[tid + 2 * Hh], ov = gates_lds[tid + 3 * Hh];
            c_state = fv * c_state + iv * gv;
            h_lds[tid] = ov * tanhf(c_state);
        } else if (tid >= 384 && tid < 448) {
            int tn = t + 1;
            if (tn < Tt) x_lds[tn & 1][tid - 384] = xB[(long)tn * Dd + (tid - 384)];
        }
        __syncthreads();
        const int w = tid >> 6, l = tid & 63;
        if (w < Cc) {
            float p = 0.0f;
            #pragma unroll
            for (int qq = 0; qq < 4; ++qq) p += h_lds[l + 64 * qq] * wout_t[w][l + 64 * qq];
            #pragma unroll
            for (int off = 32; off > 0; off >>= 1) p += __shfl_down(p, off);
            if (l == 0) out[((long)b * Tt + t) * Cc + w] = p + bout_l[w];
        }
    }
}

extern "C" void kernel_launch(void* const* d_in, const int* in_sizes, int n_in,
                              void* d_out, int out_size, void* d_ws, size_t ws_size,
                              hipStream_t stream) {
    const float* x    = (const float*)d_in[0];
    const float* Wx   = (const float*)d_in[1];
    const float* Wh   = (const float*)d_in[2];
    const float* bvec = (const float*)d_in[3];
    const float* Wout = (const float*)d_in[4];
    const float* bout = (const float*)d_in[5];
    float* outp = (float*)d_out;

    if (ws_size >= XG_BYTES) {
        unsigned short* xgws = (unsigned short*)d_ws;
        xg_gemm<<<dim3(BT / 64, 4), dim3(256), 0, stream>>>(x, Wx, bvec, xgws);
        lstm_xg<<<dim3(128), dim3(256), 0, stream>>>(xgws, Wh);
        out_proj<<<dim3(128, 4), dim3(256), 0, stream>>>(xgws, Wout, bout, outp);
    } else {
        lstm_fused<<<dim3(128), dim3(1024), 0, stream>>>(x, Wx, Wh, bvec, Wout, bout, outp);
    }
}